// Round 11
// baseline (370.989 us; speedup 1.0000x reference)
//
#include <hip/hip_runtime.h>

#define N_NODES 100000
#define N_EDGES 1600000
#define C 128
#define NCLS 40
#define NBUCK 196   // ceil(100000/512)
#define BCAP 12288  // per-bucket edge capacity (mean 8192, +45 sigma)

typedef _Float16 half8 __attribute__((ext_vector_type(8)));
typedef float f32x4 __attribute__((ext_vector_type(4)));
typedef float f32x16 __attribute__((ext_vector_type(16)));

// ================= bucketed CSR build =================

__global__ __launch_bounds__(256) void bucket_scatter_k(const int* __restrict__ src,
    const int* __restrict__ dst, int* __restrict__ bucket_cnt, int* __restrict__ bucketArr) {
  __shared__ int lh[NBUCK], lbase[NBUCK], lcur[NBUCK];
  int tid = threadIdx.x;
  for (int i = tid; i < NBUCK; i += 256) { lh[i] = 0; lcur[i] = 0; }
  __syncthreads();
  int base = blockIdx.x * 4096;
  int bmax = min(base + 4096, N_EDGES);
  int dreg[16];
  int nk = 0;
  for (int e = base + tid; e < bmax; e += 256) dreg[nk++] = dst[e];
  for (int k = 0; k < nk; k++) atomicAdd(&lh[dreg[k] >> 9], 1);
  __syncthreads();
  for (int i = tid; i < NBUCK; i += 256)
    lbase[i] = lh[i] ? atomicAdd(&bucket_cnt[i], lh[i]) : 0;
  __syncthreads();
  nk = 0;
  for (int e = base + tid; e < bmax; e += 256) {
    int d = dreg[nk++];
    int b = d >> 9, loc = d & 511;
    int p = lbase[b] + atomicAdd(&lcur[b], 1);
    if (p < BCAP) bucketArr[(size_t)b * BCAP + p] = (src[e] << 9) | loc;
  }
}

// One block per bucket; local scan of all bucket counts; LDS counting sort.
__global__ __launch_bounds__(256) void bucket_sort_k(const int* __restrict__ bucketArr,
    const int* __restrict__ bucket_cnt, int* __restrict__ rp, int* __restrict__ csr) {
  __shared__ int pref[NBUCK + 1];
  __shared__ int hist[512], offs[512], curs[512];
  __shared__ int wpart[4];
  __shared__ int lsrc[BCAP];
  int b = blockIdx.x, tid = threadIdx.x;
  int lane = tid & 63, wid = tid >> 6;

  {
    int v = (tid < NBUCK) ? min(bucket_cnt[tid], BCAP) : 0;
    int inc = v;
    for (int d = 1; d < 64; d <<= 1) { int y = __shfl_up(inc, d, 64); if (lane >= d) inc += y; }
    if (lane == 63) wpart[wid] = inc;
    __syncthreads();
    int woff = 0;
    for (int q = 0; q < wid; q++) woff += wpart[q];
    int ex = woff + inc - v;
    if (tid < NBUCK) pref[tid] = ex;
    if (tid == NBUCK - 1) pref[NBUCK] = ex + v;
    __syncthreads();
  }
  int base = pref[b];
  int cnt = min(bucket_cnt[b], BCAP);
  if (b == 0 && tid == 0) rp[N_NODES] = pref[NBUCK];
  __syncthreads();

  for (int i = tid; i < 512; i += 256) hist[i] = 0;
  __syncthreads();
  for (int i = tid; i < cnt; i += 256)
    atomicAdd(&hist[bucketArr[(size_t)b * BCAP + i] & 511], 1);
  __syncthreads();
  int a0 = hist[2 * tid], a1 = hist[2 * tid + 1];
  int s = a0 + a1;
  int inc = s;
  for (int d = 1; d < 64; d <<= 1) { int y = __shfl_up(inc, d, 64); if (lane >= d) inc += y; }
  if (lane == 63) wpart[wid] = inc;
  __syncthreads();
  int woff = 0;
  for (int q = 0; q < wid; q++) woff += wpart[q];
  int ex = woff + inc - s;
  offs[2 * tid] = ex; offs[2 * tid + 1] = ex + a0;
  curs[2 * tid] = ex; curs[2 * tid + 1] = ex + a0;
  __syncthreads();
  for (int i = tid; i < 512; i += 256) {
    int gn = b * 512 + i;
    if (gn < N_NODES) rp[gn] = base + offs[i];
  }
  for (int i = tid; i < cnt; i += 256) {
    int packed = bucketArr[(size_t)b * BCAP + i];
    int p = atomicAdd(&curs[packed & 511], 1);
    lsrc[p] = packed >> 9;
  }
  __syncthreads();
  for (int i = tid; i < cnt; i += 256) csr[base + i] = lsrc[i];
}

// ============ merged: fp32->f16 convert (blocks 0-6249) + weight prep (6250-6553) ============

__global__ __launch_bounds__(256) void prep_k(const float* __restrict__ x,
    const float* __restrict__ Ws1, const float* __restrict__ Wn1,
    const float* __restrict__ Ws2, const float* __restrict__ Wn2,
    const float* __restrict__ Wc, const float* __restrict__ bc,
    _Float16* __restrict__ xh, _Float16* __restrict__ WT1, _Float16* __restrict__ WT2,
    _Float16* __restrict__ WcT, float* __restrict__ bcf) {
  int bid = blockIdx.x, tid = threadIdx.x;
  if (bid < 6250) {
    int i = bid * 256 + tid;
    float4 v0 = *(const float4*)(x + (size_t)i * 8);
    float4 v1 = *(const float4*)(x + (size_t)i * 8 + 4);
    half8 o;
    o[0] = (_Float16)v0.x; o[1] = (_Float16)v0.y; o[2] = (_Float16)v0.z; o[3] = (_Float16)v0.w;
    o[4] = (_Float16)v1.x; o[5] = (_Float16)v1.y; o[6] = (_Float16)v1.z; o[7] = (_Float16)v1.w;
    *(half8*)(xh + (size_t)i * 8) = o;
    return;
  }
  int b = bid - 6250, k = tid;
  if (b < 128) {
    float v = (k < 128) ? Ws1[k * 128 + b] : Wn1[(k - 128) * 128 + b];
    WT1[b * 256 + k] = (_Float16)v;
  } else if (b < 256) {
    int n = b - 128;
    float v = (k < 128) ? Ws2[k * 128 + n] : Wn2[(k - 128) * 128 + n];
    WT2[n * 256 + k] = (_Float16)v;
  } else if (k < 128) {
    int c = b - 256;
    float v = (c < NCLS) ? Wc[k * NCLS + c] : 0.f;
    WcT[c * C + k] = (_Float16)v;
    if (k == 0) bcf[c] = (c < NCLS) ? bc[c] : 0.f;
  }
}

// ================= mean aggregation (csr-broadcast) =================
// wave = 1 node; 16 lanes/node: 4 edge slots (g) x 16 feature chunks (lr).
// One wave-wide csr load covers the first 64 edges; indices via __shfl ->
// all feature loads independent after a single csr memory round.

__global__ __launch_bounds__(256) void agg_mean_h_k(const _Float16* __restrict__ feat,
    const int* __restrict__ rp, const int* __restrict__ csr, _Float16* __restrict__ out) {
  int w = threadIdx.x >> 6;
  int node = blockIdx.x * 4 + w;
  int lane = threadIdx.x & 63;
  int g = lane >> 4, lr = lane & 15;
  int beg = rp[node], end = rp[node + 1];
  int deg = end - beg;
  int csrv = (beg + lane < end) ? csr[beg + lane] : 0;

  half8 h0 = {}, h1 = {}, h2 = {}, h3 = {};
  int dcap = min(deg, 64);
  int nfull = dcap >> 2;
  int it = 0;
  for (; it + 4 <= nfull; it += 4) {
    int e0 = __shfl(csrv, (it << 2) + g, 64);
    int e1 = __shfl(csrv, ((it + 1) << 2) + g, 64);
    int e2 = __shfl(csrv, ((it + 2) << 2) + g, 64);
    int e3 = __shfl(csrv, ((it + 3) << 2) + g, 64);
    h0 += *(const half8*)(feat + (size_t)e0 * C + lr * 8);
    h1 += *(const half8*)(feat + (size_t)e1 * C + lr * 8);
    h2 += *(const half8*)(feat + (size_t)e2 * C + lr * 8);
    h3 += *(const half8*)(feat + (size_t)e3 * C + lr * 8);
  }
  for (; it < nfull; it++) {
    int e0 = __shfl(csrv, (it << 2) + g, 64);
    h0 += *(const half8*)(feat + (size_t)e0 * C + lr * 8);
  }
  int rem = dcap & 3;
  if (rem) {
    int e0 = __shfl(csrv, (nfull << 2) + g, 64);
    if (g < rem) h1 += *(const half8*)(feat + (size_t)e0 * C + lr * 8);
  }
  // deg > 64 safety tail
  for (int j = beg + 64; j < end; j += 4) {
    if (j + g < end) {
      int e0 = csr[j + g];
      h2 += *(const half8*)(feat + (size_t)e0 * C + lr * 8);
    }
  }

  float acc[8];
#pragma unroll
  for (int q = 0; q < 8; q++)
    acc[q] = ((float)h0[q] + (float)h1[q]) + ((float)h2[q] + (float)h3[q]);
#pragma unroll
  for (int q = 0; q < 8; q++) {
    float v = acc[q];
    v += __shfl_xor(v, 16, 64);
    v += __shfl_xor(v, 32, 64);
    acc[q] = v;
  }
  if (g == 0) {
    float inv = 1.0f / fmaxf((float)deg, 1.0f);
    half8 o;
#pragma unroll
    for (int q = 0; q < 8; q++) o[q] = (_Float16)(acc[q] * inv);
    *(half8*)(out + (size_t)node * C + lr * 8) = o;
  }
}

// ================= weights-stationary fused SAGE GEMM (+ optional classifier) ==========
// One 32-row tile per block. __launch_bounds__(256, 2): caps waves/EU at 2 ->
// VGPR budget 256/thread, so all 33 fragment loads (128+ VGPR of values) can
// coexist in flight -> ONE memory round per block (R10's VGPR=76 showed the
// default allocator serializing into ~8 rounds).
// MFMA 32x32x16 C/D: col=lane&31, row=(q&3)+8*(q>>2)+4*(lane>>5)  [m74/m101].
// MFMA 16x16x32 C/D: col=lane&15, row=(lane>>4)*4+q  [m89/m91].

template <bool CLS>
__global__ __launch_bounds__(256, 2) void sage_gemm_ws_k(
    const _Float16* __restrict__ Xs, const _Float16* __restrict__ Xn,
    const _Float16* __restrict__ WT, const float* __restrict__ bias,
    const _Float16* __restrict__ WcT, const float* __restrict__ bcf,
    _Float16* __restrict__ out_h, float* __restrict__ out_cls) {
  __shared__ _Float16 cbuf[32][136];
  int tid = threadIdx.x, lane = tid & 63, wid = tid >> 6;
  int l31 = lane & 31, l5 = lane >> 5;
  int col0 = wid * 32;
  size_t row0 = (size_t)blockIdx.x * 32;

  half8 a[16], b[16];
#pragma unroll
  for (int ks = 0; ks < 8; ks++) {
    a[ks] = *(const half8*)(Xs + (row0 + l31) * C + ks * 16 + l5 * 8);
    b[ks] = *(const half8*)(WT + (size_t)(col0 + l31) * 256 + ks * 16 + l5 * 8);
  }
#pragma unroll
  for (int ks = 8; ks < 16; ks++) {
    a[ks] = *(const half8*)(Xn + (row0 + l31) * C + (ks - 8) * 16 + l5 * 8);
    b[ks] = *(const half8*)(WT + (size_t)(col0 + l31) * 256 + ks * 16 + l5 * 8);
  }
  float bcol = bias[col0 + l31];
  __builtin_amdgcn_sched_barrier(0);  // loads stay issued ahead of all MFMAs

  f32x16 acc = {};
#pragma unroll
  for (int ks = 0; ks < 16; ks++)
    acc = __builtin_amdgcn_mfma_f32_32x32x16_f16(a[ks], b[ks], acc, 0, 0, 0);

#pragma unroll
  for (int q = 0; q < 16; q++) {
    int row = (q & 3) + 8 * (q >> 2) + 4 * l5;
    float v = fmaxf(acc[q] + bcol, 0.f);
    cbuf[row][col0 + l31] = (_Float16)v;
  }
  __syncthreads();

  if (!CLS) {
#pragma unroll
    for (int p = 0; p < 2; p++) {
      int chunk = tid + p * 256;
      int r = chunk >> 4, cg = chunk & 15;
      half8 v = *(const half8*)&cbuf[r][cg * 8];
      *(half8*)(out_h + (row0 + r) * C + cg * 8) = v;
    }
  } else if (wid < 2) {
    int lr16 = lane & 15, lk = lane >> 4;
    f32x4 cacc[3] = {};
#pragma unroll
    for (int ks = 0; ks < 4; ks++) {
      half8 av = *(const half8*)(&cbuf[wid * 16 + lr16][ks * 32 + lk * 8]);
#pragma unroll
      for (int nf = 0; nf < 3; nf++) {
        half8 bf = *(const half8*)(WcT + (size_t)(nf * 16 + lr16) * C + ks * 32 + lk * 8);
        cacc[nf] = __builtin_amdgcn_mfma_f32_16x16x32_f16(av, bf, cacc[nf], 0, 0, 0);
      }
    }
#pragma unroll
    for (int nf = 0; nf < 3; nf++) {
      int c = nf * 16 + lr16;
      if (c < NCLS) {
#pragma unroll
        for (int q = 0; q < 4; q++) {
          size_t r = row0 + wid * 16 + lk * 4 + q;
          out_cls[r * NCLS + c] = cacc[nf][q] + bcf[c];
        }
      }
    }
  }
}

// ================= launch =================

extern "C" void kernel_launch(void* const* d_in, const int* in_sizes, int n_in,
                              void* d_out, int out_size, void* d_ws, size_t ws_size,
                              hipStream_t stream) {
  (void)in_sizes; (void)n_in; (void)out_size; (void)ws_size;
  const float* x   = (const float*)d_in[0];
  const int*   ei  = (const int*)d_in[1];
  const float* Ws1 = (const float*)d_in[2];
  const float* Wn1 = (const float*)d_in[3];
  const float* b1  = (const float*)d_in[4];
  const float* Ws2 = (const float*)d_in[5];
  const float* Wn2 = (const float*)d_in[6];
  const float* b2  = (const float*)d_in[7];
  const float* Wc  = (const float*)d_in[8];
  const float* bc  = (const float*)d_in[9];
  const int* src = ei;
  const int* dst = ei + N_EDGES;

  char* ws = (char*)d_ws;
  size_t off = 0;
  auto alloc = [&](size_t bytes) {
    void* p = ws + off;
    off = (off + bytes + 255) & ~(size_t)255;
    return p;
  };
  int*      bucket_cnt  = (int*)alloc((size_t)NBUCK * 4);
  int*      bucketArr   = (int*)alloc((size_t)NBUCK * BCAP * 4);
  int*      rp          = (int*)alloc((size_t)(N_NODES + 1) * 4);
  int*      csr         = (int*)alloc((size_t)N_EDGES * 4);
  _Float16* hA          = (_Float16*)alloc((size_t)N_NODES * C * 2);  // x (f16)
  _Float16* hB          = (_Float16*)alloc((size_t)N_NODES * C * 2);  // agg outputs
  _Float16* hC          = (_Float16*)alloc((size_t)N_NODES * C * 2);  // h1
  _Float16* WT1         = (_Float16*)alloc((size_t)C * 256 * 2);
  _Float16* WT2         = (_Float16*)alloc((size_t)C * 256 * 2);
  _Float16* WcT         = (_Float16*)alloc((size_t)48 * C * 2);
  float*    bcf         = (float*)alloc(48 * 4);
  float* outf = (float*)d_out;

  // CSR build
  hipMemsetAsync(bucket_cnt, 0, (size_t)NBUCK * 4, stream);
  bucket_scatter_k<<<(N_EDGES + 4095) / 4096, 256, 0, stream>>>(src, dst, bucket_cnt, bucketArr);
  bucket_sort_k<<<NBUCK, 256, 0, stream>>>(bucketArr, bucket_cnt, rp, csr);

  // x conversion + weight prep (merged)
  prep_k<<<6554, 256, 0, stream>>>(x, Ws1, Wn1, Ws2, Wn2, Wc, bc, hA, WT1, WT2, WcT, bcf);

  // layer 1
  agg_mean_h_k<<<N_NODES / 4, 256, 0, stream>>>(hA, rp, csr, hB);
  sage_gemm_ws_k<false><<<3125, 256, 0, stream>>>(hA, hB, WT1, b1, nullptr, nullptr, hC, nullptr);
  // layer 2 + fused classifier (h2 never leaves LDS)
  agg_mean_h_k<<<N_NODES / 4, 256, 0, stream>>>(hC, rp, csr, hB);
  sage_gemm_ws_k<true><<<3125, 256, 0, stream>>>(hC, hB, WT2, b2, WcT, bcf, nullptr, outf);
}

// Round 12
// 300.154 us; speedup vs baseline: 1.2360x; 1.2360x over previous
//
#include <hip/hip_runtime.h>

#define N_NODES 100000
#define N_EDGES 1600000
#define C 128
#define NCLS 40
#define NBUCK 196   // ceil(100000/512)
#define BCAP 12288  // per-bucket edge capacity (mean 8192, +45 sigma)

typedef _Float16 half8 __attribute__((ext_vector_type(8)));
typedef float f32x4 __attribute__((ext_vector_type(4)));
typedef float f32x16 __attribute__((ext_vector_type(16)));

// ================= bucketed CSR build =================

__global__ __launch_bounds__(256) void bucket_scatter_k(const int* __restrict__ src,
    const int* __restrict__ dst, int* __restrict__ bucket_cnt, int* __restrict__ bucketArr) {
  __shared__ int lh[NBUCK], lbase[NBUCK], lcur[NBUCK];
  int tid = threadIdx.x;
  for (int i = tid; i < NBUCK; i += 256) { lh[i] = 0; lcur[i] = 0; }
  __syncthreads();
  int base = blockIdx.x * 4096;
  int bmax = min(base + 4096, N_EDGES);
  int dreg[16];
  int nk = 0;
  for (int e = base + tid; e < bmax; e += 256) dreg[nk++] = dst[e];
  for (int k = 0; k < nk; k++) atomicAdd(&lh[dreg[k] >> 9], 1);
  __syncthreads();
  for (int i = tid; i < NBUCK; i += 256)
    lbase[i] = lh[i] ? atomicAdd(&bucket_cnt[i], lh[i]) : 0;
  __syncthreads();
  nk = 0;
  for (int e = base + tid; e < bmax; e += 256) {
    int d = dreg[nk++];
    int b = d >> 9, loc = d & 511;
    int p = lbase[b] + atomicAdd(&lcur[b], 1);
    if (p < BCAP) bucketArr[(size_t)b * BCAP + p] = (src[e] << 9) | loc;
  }
}

// One block per bucket; local scan of all bucket counts; LDS counting sort.
__global__ __launch_bounds__(256) void bucket_sort_k(const int* __restrict__ bucketArr,
    const int* __restrict__ bucket_cnt, int* __restrict__ rp, int* __restrict__ csr) {
  __shared__ int pref[NBUCK + 1];
  __shared__ int hist[512], offs[512], curs[512];
  __shared__ int wpart[4];
  __shared__ int lsrc[BCAP];
  int b = blockIdx.x, tid = threadIdx.x;
  int lane = tid & 63, wid = tid >> 6;

  {
    int v = (tid < NBUCK) ? min(bucket_cnt[tid], BCAP) : 0;
    int inc = v;
    for (int d = 1; d < 64; d <<= 1) { int y = __shfl_up(inc, d, 64); if (lane >= d) inc += y; }
    if (lane == 63) wpart[wid] = inc;
    __syncthreads();
    int woff = 0;
    for (int q = 0; q < wid; q++) woff += wpart[q];
    int ex = woff + inc - v;
    if (tid < NBUCK) pref[tid] = ex;
    if (tid == NBUCK - 1) pref[NBUCK] = ex + v;
    __syncthreads();
  }
  int base = pref[b];
  int cnt = min(bucket_cnt[b], BCAP);
  if (b == 0 && tid == 0) rp[N_NODES] = pref[NBUCK];
  __syncthreads();

  for (int i = tid; i < 512; i += 256) hist[i] = 0;
  __syncthreads();
  for (int i = tid; i < cnt; i += 256)
    atomicAdd(&hist[bucketArr[(size_t)b * BCAP + i] & 511], 1);
  __syncthreads();
  int a0 = hist[2 * tid], a1 = hist[2 * tid + 1];
  int s = a0 + a1;
  int inc = s;
  for (int d = 1; d < 64; d <<= 1) { int y = __shfl_up(inc, d, 64); if (lane >= d) inc += y; }
  if (lane == 63) wpart[wid] = inc;
  __syncthreads();
  int woff = 0;
  for (int q = 0; q < wid; q++) woff += wpart[q];
  int ex = woff + inc - s;
  offs[2 * tid] = ex; offs[2 * tid + 1] = ex + a0;
  curs[2 * tid] = ex; curs[2 * tid + 1] = ex + a0;
  __syncthreads();
  for (int i = tid; i < 512; i += 256) {
    int gn = b * 512 + i;
    if (gn < N_NODES) rp[gn] = base + offs[i];
  }
  for (int i = tid; i < cnt; i += 256) {
    int packed = bucketArr[(size_t)b * BCAP + i];
    int p = atomicAdd(&curs[packed & 511], 1);
    lsrc[p] = packed >> 9;
  }
  __syncthreads();
  for (int i = tid; i < cnt; i += 256) csr[base + i] = lsrc[i];
}

// ============ merged prep: fp32->f16 x (blocks 0-6249) + weights (6250-6553) ============
// WT is stored in MFMA-fragment order ("WTp"): element B[k][n] for the wave
// covering col-block cb, k-step ks lives at WTp[(cb*16+ks)*512 + lane*8 + j]
// with lane = (k_in_step>>3)*32 + (n&31), j = k&7  ->  each wave's b[ks] load
// is ONE contiguous 1KB read (16 fully-used lines vs 64 quarter-used strided).

__global__ __launch_bounds__(256) void prep_k(const float* __restrict__ x,
    const float* __restrict__ Ws1, const float* __restrict__ Wn1,
    const float* __restrict__ Ws2, const float* __restrict__ Wn2,
    const float* __restrict__ Wc, const float* __restrict__ bc,
    _Float16* __restrict__ xh, _Float16* __restrict__ WTp1, _Float16* __restrict__ WTp2,
    _Float16* __restrict__ WcT, float* __restrict__ bcf) {
  int bid = blockIdx.x, tid = threadIdx.x;
  if (bid < 6250) {
    int i = bid * 256 + tid;
    float4 v0 = *(const float4*)(x + (size_t)i * 8);
    float4 v1 = *(const float4*)(x + (size_t)i * 8 + 4);
    half8 o;
    o[0] = (_Float16)v0.x; o[1] = (_Float16)v0.y; o[2] = (_Float16)v0.z; o[3] = (_Float16)v0.w;
    o[4] = (_Float16)v1.x; o[5] = (_Float16)v1.y; o[6] = (_Float16)v1.z; o[7] = (_Float16)v1.w;
    *(half8*)(xh + (size_t)i * 8) = o;
    return;
  }
  int b = bid - 6250, k = tid;  // b = output col n (0-127), k = K index (0-255)
  if (b < 128) {
    float v = (k < 128) ? Ws1[k * 128 + b] : Wn1[(k - 128) * 128 + b];
    int cb = b >> 5, l31 = b & 31, ks = k >> 4, l5 = (k >> 3) & 1, j = k & 7;
    WTp1[(size_t)(cb * 16 + ks) * 512 + (l5 * 32 + l31) * 8 + j] = (_Float16)v;
  } else if (b < 256) {
    int n = b - 128;
    float v = (k < 128) ? Ws2[k * 128 + n] : Wn2[(k - 128) * 128 + n];
    int cb = n >> 5, l31 = n & 31, ks = k >> 4, l5 = (k >> 3) & 1, j = k & 7;
    WTp2[(size_t)(cb * 16 + ks) * 512 + (l5 * 32 + l31) * 8 + j] = (_Float16)v;
  } else if (k < 128) {
    int c = b - 256;
    float v = (c < NCLS) ? Wc[k * NCLS + c] : 0.f;
    WcT[c * C + k] = (_Float16)v;
    if (k == 0) bcf[c] = (c < NCLS) ? bc[c] : 0.f;
  }
}

// ================= mean aggregation (csr-broadcast) =================

__global__ __launch_bounds__(256) void agg_mean_h_k(const _Float16* __restrict__ feat,
    const int* __restrict__ rp, const int* __restrict__ csr, _Float16* __restrict__ out) {
  int w = threadIdx.x >> 6;
  int node = blockIdx.x * 4 + w;
  int lane = threadIdx.x & 63;
  int g = lane >> 4, lr = lane & 15;
  int beg = rp[node], end = rp[node + 1];
  int deg = end - beg;
  int csrv = (beg + lane < end) ? csr[beg + lane] : 0;

  half8 h0 = {}, h1 = {}, h2 = {}, h3 = {};
  int dcap = min(deg, 64);
  int nfull = dcap >> 2;
  int it = 0;
  for (; it + 4 <= nfull; it += 4) {
    int e0 = __shfl(csrv, (it << 2) + g, 64);
    int e1 = __shfl(csrv, ((it + 1) << 2) + g, 64);
    int e2 = __shfl(csrv, ((it + 2) << 2) + g, 64);
    int e3 = __shfl(csrv, ((it + 3) << 2) + g, 64);
    h0 += *(const half8*)(feat + (size_t)e0 * C + lr * 8);
    h1 += *(const half8*)(feat + (size_t)e1 * C + lr * 8);
    h2 += *(const half8*)(feat + (size_t)e2 * C + lr * 8);
    h3 += *(const half8*)(feat + (size_t)e3 * C + lr * 8);
  }
  for (; it < nfull; it++) {
    int e0 = __shfl(csrv, (it << 2) + g, 64);
    h0 += *(const half8*)(feat + (size_t)e0 * C + lr * 8);
  }
  int rem = dcap & 3;
  if (rem) {
    int e0 = __shfl(csrv, (nfull << 2) + g, 64);
    if (g < rem) h1 += *(const half8*)(feat + (size_t)e0 * C + lr * 8);
  }
  // deg > 64 safety tail
  for (int j = beg + 64; j < end; j += 4) {
    if (j + g < end) {
      int e0 = csr[j + g];
      h2 += *(const half8*)(feat + (size_t)e0 * C + lr * 8);
    }
  }

  float acc[8];
#pragma unroll
  for (int q = 0; q < 8; q++)
    acc[q] = ((float)h0[q] + (float)h1[q]) + ((float)h2[q] + (float)h3[q]);
#pragma unroll
  for (int q = 0; q < 8; q++) {
    float v = acc[q];
    v += __shfl_xor(v, 16, 64);
    v += __shfl_xor(v, 32, 64);
    acc[q] = v;
  }
  if (g == 0) {
    float inv = 1.0f / fmaxf((float)deg, 1.0f);
    half8 o;
#pragma unroll
    for (int q = 0; q < 8; q++) o[q] = (_Float16)(acc[q] * inv);
    *(half8*)(out + (size_t)node * C + lr * 8) = o;
  }
}

// ========== LDS-staged weights-stationary SAGE GEMM (+ optional classifier) ==========
// Fixes the 4-round invariant: ALL global traffic is line-coalesced.
//  - A tile (32 rows x 256 k, 16KB): each thread loads 16B CONTIGUOUS from
//    Xs/Xn, stores to LDS at XOR-swizzled byte (p ^ ((row&7)<<4)); the XOR
//    stays within a 128B block so line-coalescing is preserved and the
//    Xs/Xn halves never mix. Fragment ds_read_b128 applies the same XOR
//    -> 4-way residual bank conflict (1.58x, m136).
//  - B fragments from fragment-ordered WTp: 1KB contiguous per wave per ks.
// MFMA 32x32x16 C/D: col=lane&31, row=(q&3)+8*(q>>2)+4*(lane>>5)  [m74/m101].
// MFMA 16x16x32 C/D: col=lane&15, row=(lane>>4)*4+q  [m89/m91].

template <bool CLS>
__global__ __launch_bounds__(256, 3) void sage_gemm_lds_k(
    const _Float16* __restrict__ Xs, const _Float16* __restrict__ Xn,
    const _Float16* __restrict__ WTp, const float* __restrict__ bias,
    const _Float16* __restrict__ WcT, const float* __restrict__ bcf,
    _Float16* __restrict__ out_h, float* __restrict__ out_cls) {
  __shared__ _Float16 As[32 * 256];   // 16 KB, XOR-swizzled
  __shared__ _Float16 cbuf[32][136];
  int tid = threadIdx.x, lane = tid & 63, wid = tid >> 6;
  int l31 = lane & 31, l5 = lane >> 5;
  int col0 = wid * 32;
  size_t row0 = (size_t)blockIdx.x * 32;

  // B fragments: 16 contiguous 1KB/wave loads (L2-hot, issued first)
  half8 b[16];
#pragma unroll
  for (int ks = 0; ks < 16; ks++)
    b[ks] = *(const half8*)(WTp + (size_t)(wid * 16 + ks) * 512 + lane * 8);
  float bcol = bias[col0 + l31];

  // stage A tile: contiguous global reads, swizzled LDS placement
#pragma unroll
  for (int it = 0; it < 4; it++) {
    int off = it * 4096 + tid * 16;      // phys byte offset in tile
    int row = off >> 9;                  // 512 B per row
    int p = off & 511;
    int c = p ^ ((row & 7) << 4);        // logical col (bytes); stays in 128B block
    const _Float16* srcp = (c < 256) ? (Xs + (row0 + row) * C + (c >> 1))
                                     : (Xn + (row0 + row) * C + ((c - 256) >> 1));
    *(half8*)((char*)As + off) = *(const half8*)srcp;
  }
  __syncthreads();

  f32x16 acc = {};
#pragma unroll
  for (int ks = 0; ks < 16; ks++) {
    int phys = (ks * 32 + l5 * 16) ^ ((l31 & 7) << 4);
    half8 a = *(const half8*)((const char*)As + l31 * 512 + phys);
    acc = __builtin_amdgcn_mfma_f32_32x32x16_f16(a, b[ks], acc, 0, 0, 0);
  }

#pragma unroll
  for (int q = 0; q < 16; q++) {
    int row = (q & 3) + 8 * (q >> 2) + 4 * l5;
    float v = fmaxf(acc[q] + bcol, 0.f);
    cbuf[row][col0 + l31] = (_Float16)v;
  }
  __syncthreads();

  if (!CLS) {
#pragma unroll
    for (int p = 0; p < 2; p++) {
      int chunk = tid + p * 256;
      int r = chunk >> 4, cg = chunk & 15;
      half8 v = *(const half8*)&cbuf[r][cg * 8];
      *(half8*)(out_h + (row0 + r) * C + cg * 8) = v;
    }
  } else if (wid < 2) {
    int lr16 = lane & 15, lk = lane >> 4;
    f32x4 cacc[3] = {};
#pragma unroll
    for (int ks = 0; ks < 4; ks++) {
      half8 av = *(const half8*)(&cbuf[wid * 16 + lr16][ks * 32 + lk * 8]);
#pragma unroll
      for (int nf = 0; nf < 3; nf++) {
        half8 bf = *(const half8*)(WcT + (size_t)(nf * 16 + lr16) * C + ks * 32 + lk * 8);
        cacc[nf] = __builtin_amdgcn_mfma_f32_16x16x32_f16(av, bf, cacc[nf], 0, 0, 0);
      }
    }
#pragma unroll
    for (int nf = 0; nf < 3; nf++) {
      int c = nf * 16 + lr16;
      if (c < NCLS) {
#pragma unroll
        for (int q = 0; q < 4; q++) {
          size_t r = row0 + wid * 16 + lk * 4 + q;
          out_cls[r * NCLS + c] = cacc[nf][q] + bcf[c];
        }
      }
    }
  }
}

// ================= launch =================

extern "C" void kernel_launch(void* const* d_in, const int* in_sizes, int n_in,
                              void* d_out, int out_size, void* d_ws, size_t ws_size,
                              hipStream_t stream) {
  (void)in_sizes; (void)n_in; (void)out_size; (void)ws_size;
  const float* x   = (const float*)d_in[0];
  const int*   ei  = (const int*)d_in[1];
  const float* Ws1 = (const float*)d_in[2];
  const float* Wn1 = (const float*)d_in[3];
  const float* b1  = (const float*)d_in[4];
  const float* Ws2 = (const float*)d_in[5];
  const float* Wn2 = (const float*)d_in[6];
  const float* b2  = (const float*)d_in[7];
  const float* Wc  = (const float*)d_in[8];
  const float* bc  = (const float*)d_in[9];
  const int* src = ei;
  const int* dst = ei + N_EDGES;

  char* ws = (char*)d_ws;
  size_t off = 0;
  auto alloc = [&](size_t bytes) {
    void* p = ws + off;
    off = (off + bytes + 255) & ~(size_t)255;
    return p;
  };
  int*      bucket_cnt  = (int*)alloc((size_t)NBUCK * 4);
  int*      bucketArr   = (int*)alloc((size_t)NBUCK * BCAP * 4);
  int*      rp          = (int*)alloc((size_t)(N_NODES + 1) * 4);
  int*      csr         = (int*)alloc((size_t)N_EDGES * 4);
  _Float16* hA          = (_Float16*)alloc((size_t)N_NODES * C * 2);  // x (f16)
  _Float16* hB          = (_Float16*)alloc((size_t)N_NODES * C * 2);  // agg outputs
  _Float16* hC          = (_Float16*)alloc((size_t)N_NODES * C * 2);  // h1
  _Float16* WTp1        = (_Float16*)alloc((size_t)C * 256 * 2);      // fragment-order
  _Float16* WTp2        = (_Float16*)alloc((size_t)C * 256 * 2);
  _Float16* WcT         = (_Float16*)alloc((size_t)48 * C * 2);
  float*    bcf         = (float*)alloc(48 * 4);
  float* outf = (float*)d_out;

  // CSR build
  hipMemsetAsync(bucket_cnt, 0, (size_t)NBUCK * 4, stream);
  bucket_scatter_k<<<(N_EDGES + 4095) / 4096, 256, 0, stream>>>(src, dst, bucket_cnt, bucketArr);
  bucket_sort_k<<<NBUCK, 256, 0, stream>>>(bucketArr, bucket_cnt, rp, csr);

  // x conversion + weight prep (merged)
  prep_k<<<6554, 256, 0, stream>>>(x, Ws1, Wn1, Ws2, Wn2, Wc, bc, hA, WTp1, WTp2, WcT, bcf);

  // layer 1
  agg_mean_h_k<<<N_NODES / 4, 256, 0, stream>>>(hA, rp, csr, hB);
  sage_gemm_lds_k<false><<<3125, 256, 0, stream>>>(hA, hB, WTp1, b1, nullptr, nullptr, hC, nullptr);
  // layer 2 + fused classifier (h2 never leaves LDS)
  agg_mean_h_k<<<N_NODES / 4, 256, 0, stream>>>(hC, rp, csr, hB);
  sage_gemm_lds_k<true><<<3125, 256, 0, stream>>>(hC, hB, WTp2, b2, WcT, bcf, nullptr, outf);
}